// Round 5
// baseline (171.359 us; speedup 1.0000x reference)
//
#include <hip/hip_runtime.h>
#include <hip/hip_fp16.h>

// SGConvolution: out = A @ (A @ x), A sparse COO (edge_row sorted).
// N=100000, E=1600000, D=64 (== wave width; lane d owns feature d).
//
// R4 -> R5: CSR row-ownership. erow is sorted, so rowptr = lower_bound(erow,n)
// (binary search, built in the prep kernel alongside the x->fp16 cast). Each
// wave owns 4 rows: accumulates fp32 in registers, plain-stores each row once
// (round 1 stores fp16 directly -> no atomics, no memsets, no cast kernels).
// 3 dispatches total (was 6). Gathers stay fp16 (half the past-L2 traffic).

#define N_NODES 100000
#define N_EDGES 1600000
#define D_FEAT  64
#define ROWS    4                      // rows per wave; 100000/4 = 25000 waves

__device__ __forceinline__ float readlane_f(float x, int j) {
    return __uint_as_float(__builtin_amdgcn_readlane(__float_as_uint(x), j));
}

__device__ __forceinline__ void store_feat(__half* p, float v) { *p = __float2half_rn(v); }
__device__ __forceinline__ void store_feat(float*  p, float v) { *p = v; }

// Fused prep: x (fp32) -> h16 cast, plus rowptr[n] = lower_bound(erow, n).
__global__ __launch_bounds__(256) void prep_kernel(
    const float* __restrict__ x, __half* __restrict__ h16,
    const int* __restrict__ erow, int* __restrict__ rowptr)
{
    const int gid = blockIdx.x * blockDim.x + threadIdx.x;
    const int n4  = (N_NODES * D_FEAT) / 4;          // 1,600,000 cast threads
    if (gid < n4) {
        const float4 v = ((const float4*)x)[gid];
        ((__half2*)h16)[2 * gid]     = __floats2half2_rn(v.x, v.y);
        ((__half2*)h16)[2 * gid + 1] = __floats2half2_rn(v.z, v.w);
    } else {
        const int n = gid - n4;                      // 0..N_NODES inclusive
        if (n <= N_NODES) {
            int lo = 0, hi = N_EDGES;
            while (lo < hi) {
                const int mid = (lo + hi) >> 1;
                if (erow[mid] < n) lo = mid + 1; else hi = mid;
            }
            rowptr[n] = lo;
        }
    }
}

// CSR SpMM: wave w owns rows [4w, 4w+4). No atomics; each row stored once.
template <typename OutT>
__global__ __launch_bounds__(256) void sg_spmm_csr(
    const __half* __restrict__ h,        // [N, 64] fp16 feature table
    const int*    __restrict__ rowptr,   // [N+1]
    const int*    __restrict__ ecol,     // [E] source cols (grouped by row)
    const float*  __restrict__ eval,     // [E] edge weights
    OutT*         __restrict__ out)      // [N, 64] (fp16 round 1, fp32 round 2)
{
    const int lane = threadIdx.x & 63;
    const int wave = (int)((blockIdx.x * blockDim.x + threadIdx.x) >> 6);
    const int r0   = wave * ROWS;
    if (r0 >= N_NODES) return;

    int rp[ROWS + 1];
#pragma unroll
    for (int i = 0; i <= ROWS; ++i) rp[i] = rowptr[r0 + i];   // wave-uniform -> s_load

    // Preload row 0's first 64 edge triples (lane i = edge e0+i; invalid lanes
    // get col 0 / weight 0 -> harmless gather of row 0 scaled by 0).
    int c_v; float w_v;
    {
        const int e0 = rp[0], n = min(64, rp[1] - e0);
        c_v = (lane < n) ? ecol[e0 + lane] : 0;
        w_v = (lane < n) ? eval[e0 + lane] : 0.0f;
    }
    int nxt_c = 0; float nxt_w = 0.0f;

#pragma unroll
    for (int r = 0; r < ROWS; ++r) {
        // Prefetch next row's edges while this row's gathers/folds run.
        if (r + 1 < ROWS) {
            const int e0 = rp[r + 1], n = min(64, rp[r + 2] - e0);
            nxt_c = (lane < n) ? ecol[e0 + lane] : 0;
            nxt_w = (lane < n) ? eval[e0 + lane] : 0.0f;
        }

        float acc = 0.0f;
        int eb = rp[r];
        const int e1 = rp[r + 1];
        while (eb < e1) {                       // usually exactly 1 iteration
            const int n   = min(64, e1 - eb);
            const int nch = (n + 15) >> 4;      // chunks of 16 gathers
            for (int k = 0; k < nch; ++k) {
                __half g[16];
#pragma unroll
                for (int j = 0; j < 16; ++j) {  // 16 independent gathers in flight
                    const int c = __builtin_amdgcn_readlane(c_v, k * 16 + j);
                    g[j] = h[(size_t)c * D_FEAT + lane];
                }
#pragma unroll
                for (int j = 0; j < 16; ++j) {
                    acc += readlane_f(w_v, k * 16 + j) * __half2float(g[j]);
                }
            }
            eb += 64;
            if (eb < e1) {                      // rare: degree > 64
                const int n2 = min(64, e1 - eb);
                c_v = (lane < n2) ? ecol[eb + lane] : 0;
                w_v = (lane < n2) ? eval[eb + lane] : 0.0f;
            }
        }
        store_feat(&out[(size_t)(r0 + r) * D_FEAT + lane], acc);  // coalesced, once
        if (r + 1 < ROWS) { c_v = nxt_c; w_v = nxt_w; }
    }
}

// Minimal fallback if ws is too small for the fp16 path (not expected).
__global__ __launch_bounds__(256) void spmm_atomic_f32(
    const float* __restrict__ h, const int* __restrict__ erow,
    const int* __restrict__ ecol, const float* __restrict__ eval,
    float* __restrict__ out)
{
    const int lane  = threadIdx.x & 63;
    const int wave  = (int)((blockIdx.x * blockDim.x + threadIdx.x) >> 6);
    const int start = wave * 64;
    if (start >= N_EDGES) return;
    int cur_row = erow[start];
    float acc = 0.0f;
    for (int e = start; e < start + 64; ++e) {
        const int r = erow[e];
        if (r != cur_row) {
            atomicAdd(&out[(size_t)cur_row * D_FEAT + lane], acc);
            acc = 0.0f; cur_row = r;
        }
        acc += eval[e] * h[(size_t)ecol[e] * D_FEAT + lane];
    }
    atomicAdd(&out[(size_t)cur_row * D_FEAT + lane], acc);
}

extern "C" void kernel_launch(void* const* d_in, const int* in_sizes, int n_in,
                              void* d_out, int out_size, void* d_ws, size_t ws_size,
                              hipStream_t stream) {
    const float* x    = (const float*)d_in[0];
    const int*   erow = (const int*)  d_in[1];
    const int*   ecol = (const int*)  d_in[2];
    const float* eval = (const float*)d_in[3];
    float*       out  = (float*)d_out;

    const size_t n_elem    = (size_t)N_NODES * D_FEAT;            // 6.4e6
    const size_t f16_bytes = n_elem * sizeof(__half);             // 12.8 MB
    const size_t off_a     = 1 << 20;                             // rowptr pad
    const size_t off_b     = off_a + f16_bytes;
    const size_t needed    = off_b + f16_bytes;                   // ~26.7 MB

    const int threads = 256;

    if (ws_size >= needed) {
        int*    rowptr = (int*)d_ws;
        __half* h16a   = (__half*)((char*)d_ws + off_a);          // cast(x)
        __half* h16b   = (__half*)((char*)d_ws + off_b);          // h1 in fp16

        const int prep_total  = (int)(n_elem / 4) + N_NODES + 1;  // 1,700,001
        const int prep_blocks = (prep_total + threads - 1) / threads;
        const int spmm_blocks = (N_NODES / ROWS) * 64 / threads;  // 6250 exactly

        prep_kernel<<<prep_blocks, threads, 0, stream>>>(x, h16a, erow, rowptr);
        sg_spmm_csr<__half><<<spmm_blocks, threads, 0, stream>>>(
            h16a, rowptr, ecol, eval, h16b);
        sg_spmm_csr<float><<<spmm_blocks, threads, 0, stream>>>(
            h16b, rowptr, ecol, eval, out);
    } else {
        // fp32 atomic fallback (ws only fits the fp32 intermediate)
        float* h1 = (float*)d_ws;
        const size_t f32_bytes = n_elem * sizeof(float);
        hipMemsetAsync(h1, 0, f32_bytes, stream);
        hipMemsetAsync(out, 0, f32_bytes, stream);
        const int blocks = (N_EDGES / 64) * 64 / threads;
        spmm_atomic_f32<<<blocks, threads, 0, stream>>>(x, erow, ecol, eval, h1);
        spmm_atomic_f32<<<blocks, threads, 0, stream>>>(h1, erow, ecol, eval, out);
    }
}